// Round 16
// baseline (397.823 us; speedup 1.0000x reference)
//
#include <hip/hip_runtime.h>
#include <math.h>

#define N_DST   32768
#define N_EDGE  524288
#define LN_EPS  1e-5f
#define W_HALF  35840            // shorts per part: 10 kc x 7 frags x 64 lanes x 8
#define W_TOT   71680            // both parts; 143360 bytes dynamic LDS

typedef __attribute__((ext_vector_type(8))) short short8b;   // 8 bf16 (4 VGPR)
typedef __attribute__((ext_vector_type(4))) float f32x4;

static __device__ __forceinline__ unsigned short f2bf(float f) {
    unsigned u = __float_as_uint(f);
    u += 0x7fff + ((u >> 16) & 1);          // round-to-nearest-even
    return (unsigned short)(u >> 16);
}
static __device__ __forceinline__ float bf2f(unsigned short s) {
    return __uint_as_float(((unsigned)s) << 16);
}

// ---------- prep: K+V weights -> B-frag order over K'=320 (no region pad), zq, wout^T ----------
__global__ void k_prep(const float* __restrict__ wkv_w, const float* __restrict__ wq_w,
                       const float* __restrict__ wq_b, const float* __restrict__ time_b,
                       const float* __restrict__ wout_w,
                       unsigned short* __restrict__ Wvp, float* __restrict__ zq,
                       float* __restrict__ wout_t) {
    int idx = blockIdx.x * 256 + threadIdx.x;
    if (idx < W_TOT) {
        int part = idx / W_HALF, r2 = idx % W_HALF;
        int jj = r2 & 7, l = (r2 >> 3) & 63, n = (r2 >> 9) % 7, kc = r2 / 3584;
        int c = n * 16 + (l & 15);
        int k = kc * 32 + ((l >> 4) << 3) + jj;          // 0..319, real k<300
        float v = (c < 100 && k < 300)
                  ? wkv_w[(size_t)(part * 100 + c) * 300 + k] : 0.f;
        Wvp[idx] = f2bf(v);
    } else if (idx < W_TOT + 100) {
        int o = idx - W_TOT;
        float acc = wq_b[o];
        for (int j = 0; j < 100; ++j)
            acc += cosf(time_b[j]) * wq_w[o * 200 + 100 + j];
        zq[o] = acc;
    } else if (idx < W_TOT + 100 + 20000) {
        int r = idx - (W_TOT + 100);            // wout_t[i][o] = wout_w[o][i]
        wout_t[r] = wout_w[(size_t)(r % 100) * 200 + r / 100];
    }
}

// ---------- CSR offsets via binary search over sorted edge_dst ----------
__global__ void k_offsets(const int* __restrict__ dst, int* __restrict__ off) {
    int n = blockIdx.x * 256 + threadIdx.x;
    if (n > N_DST) return;
    int lo = 0, hi = N_EDGE;
    while (lo < hi) {
        int mid = (lo + hi) >> 1;
        if (dst[mid] < n) lo = mid + 1; else hi = mid;
    }
    off[n] = lo;
}

// ---------- Q = dst_h @ wq_w[:, :100].T + zq : 16 nodes/block ----------
__global__ __launch_bounds__(128) void k_q(const float* __restrict__ dst_h,
                                           const float* __restrict__ wq_w,
                                           const float* __restrict__ zq,
                                           float* __restrict__ Q) {
    __shared__ float Ds[16][100];
    int n0 = blockIdx.x * 16, t = threadIdx.x;
    for (int idx = t; idx < 1600; idx += 128)
        Ds[idx / 100][idx % 100] = dst_h[(size_t)n0 * 100 + idx];
    __syncthreads();
    if (t < 100) {
        float z = zq[t];
        float acc[16];
        #pragma unroll
        for (int n = 0; n < 16; ++n) acc[n] = z;
        const float* __restrict__ wr = wq_w + t * 200;
        for (int i = 0; i < 100; ++i) {
            float w = wr[i];
            #pragma unroll
            for (int n = 0; n < 16; ++n) acc[n] = fmaf(Ds[n][i], w, acc[n]);
        }
        #pragma unroll
        for (int n = 0; n < 16; ++n) Q[(size_t)(n0 + n) * 100 + t] = acc[n];
    }
}

// ---------- k_edge: W fully LDS-resident (140 KB dynamic), barrier-free tile stream ----------
// 1 block/CU; grid-stride over 4096 tiles of 128 edges; wave owns 2 chains of 16 edges.
// No barriers in steady state -> waves stream X from HBM continuously.
__global__ __launch_bounds__(256, 1) void k_edge(
        const float* __restrict__ src_h, const float* __restrict__ efeat,
        const float* __restrict__ td,    const int* __restrict__ edge_dst,
        const float* __restrict__ time_w, const float* __restrict__ time_b,
        const unsigned short* __restrict__ Wvp, const float* __restrict__ wkv_b,
        const float* __restrict__ Q,
        unsigned short* __restrict__ Vb, float2* __restrict__ attn) {
    extern __shared__ unsigned short Wlds[];             // [part][kc][n][64][8]
    const int t = threadIdx.x, lane = t & 63, wv = t >> 6;
    const int col = lane & 15, slice = lane >> 4;

    {   // stage ALL of W once (17920 float4 over 256 threads)
        const float4* __restrict__ s4 = (const float4*)Wvp;
        float4* __restrict__ d4 = (float4*)Wlds;
        #pragma unroll
        for (int i = 0; i < 70; ++i) d4[i * 256 + t] = s4[i * 256 + t];
    }
    __syncthreads();

    // per-chain A-frag builder over K'=320: only (kc3,s0) and (kc9,s1) straddle
    auto BUILD = [&](short8b* af, int rr, float tdv) {
        const float* __restrict__ sr = src_h + (size_t)rr * 100;
        const float* __restrict__ ef = efeat + (size_t)rr * 100;
        const float4 z4 = make_float4(0.f, 0.f, 0.f, 0.f);
        #pragma unroll
        for (int kc = 0; kc < 10; ++kc) {
            const int k0 = kc * 32 + slice * 8;
            float4 xa = z4, xb = z4;
            if (kc <= 2) {
                xa = *(const float4*)(sr + k0); xb = *(const float4*)(sr + k0 + 4);
            } else if (kc == 3) {
                if (slice == 0) { xa = *(const float4*)(sr + 96); xb = *(const float4*)(ef); }
                else { xa = *(const float4*)(ef + k0 - 100); xb = *(const float4*)(ef + k0 - 96); }
            } else if (kc <= 5) {
                xa = *(const float4*)(ef + k0 - 100); xb = *(const float4*)(ef + k0 - 96);
            } else {
                int o = -1, cnt = 0;                     // tf segment: cos(td*w+b)
                if (kc == 6) {
                    if (slice == 0) { xa = *(const float4*)(ef + 92); xb = *(const float4*)(ef + 96); }
                    else { o = k0 - 200; cnt = 8; }
                } else if (kc <= 8) { o = k0 - 200; cnt = 8; }
                else {                                   // kc9: k 288..319
                    if (slice == 0) { o = 88; cnt = 8; }
                    else if (slice == 1) { o = 96; cnt = 4; }
                }
                if (cnt > 0) {
                    float4 tw = *(const float4*)(time_w + o);
                    float4 tb = *(const float4*)(time_b + o);
                    xa.x = __cosf(fmaf(tdv, tw.x, tb.x)); xa.y = __cosf(fmaf(tdv, tw.y, tb.y));
                    xa.z = __cosf(fmaf(tdv, tw.z, tb.z)); xa.w = __cosf(fmaf(tdv, tw.w, tb.w));
                    if (cnt == 8) {
                        float4 tw2 = *(const float4*)(time_w + o + 4);
                        float4 tb2 = *(const float4*)(time_b + o + 4);
                        xb.x = __cosf(fmaf(tdv, tw2.x, tb2.x)); xb.y = __cosf(fmaf(tdv, tw2.y, tb2.y));
                        xb.z = __cosf(fmaf(tdv, tw2.z, tb2.z)); xb.w = __cosf(fmaf(tdv, tw2.w, tb2.w));
                    }
                }
            }
            short8b a;
            a[0] = (short)f2bf(xa.x); a[1] = (short)f2bf(xa.y);
            a[2] = (short)f2bf(xa.z); a[3] = (short)f2bf(xa.w);
            a[4] = (short)f2bf(xb.x); a[5] = (short)f2bf(xb.y);
            a[6] = (short)f2bf(xb.z); a[7] = (short)f2bf(xb.w);
            af[kc] = a;
        }
    };

    for (int tile = blockIdx.x; tile < N_EDGE / 128; tile += gridDim.x) {
        const int g0 = tile * 8 + wv * 2;
        const int r0 = g0 * 16 + col, r1 = r0 + 16;
        const int re0 = g0 * 16 + (slice << 2), re1 = re0 + 16;

        short8b af0[10], af1[10];
        BUILD(af0, r0, td[r0]);
        BUILD(af1, r1, td[r1]);

        f32x4 acc0[7], acc1[7];

        // ---------- PART 0: K (logits; K never leaves registers) ----------
        #pragma unroll
        for (int n = 0; n < 7; ++n) {
            int cl = n * 16 + col;
            float b = (cl < 100) ? wkv_b[cl] : 0.f;
            acc0[n] = (f32x4){b, b, b, b};
            acc1[n] = (f32x4){b, b, b, b};
        }
        #pragma unroll
        for (int kc = 0; kc < 10; ++kc) {
            #pragma unroll
            for (int n = 0; n < 7; ++n) {
                short8b w = *(const short8b*)(&Wlds[(size_t)((kc * 7 + n) * 64 + lane) * 8]);
                acc0[n] = __builtin_amdgcn_mfma_f32_16x16x32_bf16(af0[kc], w, acc0[n], 0, 0, 0);
                acc1[n] = __builtin_amdgcn_mfma_f32_16x16x32_bf16(af1[kc], w, acc1[n], 0, 0, 0);
            }
        }
        {   // K epilogue: logit = Q[dst] . K  (per chain)
            int d0r[4], d1r[4];
            #pragma unroll
            for (int r = 0; r < 4; ++r) { d0r[r] = edge_dst[re0 + r]; d1r[r] = edge_dst[re1 + r]; }
            float p00[4] = {0,0,0,0}, p01[4] = {0,0,0,0};
            float p10[4] = {0,0,0,0}, p11[4] = {0,0,0,0};
            #pragma unroll
            for (int n = 0; n < 7; ++n) {
                int cl = n * 16 + col;
                if (cl < 100) {
                    bool h0 = (cl < 50);
                    #pragma unroll
                    for (int r = 0; r < 4; ++r) {
                        float q0 = Q[(size_t)d0r[r] * 100 + cl];
                        float q1 = Q[(size_t)d1r[r] * 100 + cl];
                        if (h0) { p00[r] = fmaf(q0, acc0[n][r], p00[r]);
                                  p10[r] = fmaf(q1, acc1[n][r], p10[r]); }
                        else    { p01[r] = fmaf(q0, acc0[n][r], p01[r]);
                                  p11[r] = fmaf(q1, acc1[n][r], p11[r]); }
                    }
                }
            }
            #pragma unroll
            for (int r = 0; r < 4; ++r) {
                #pragma unroll
                for (int sh = 1; sh < 16; sh <<= 1) {
                    p00[r] += __shfl_xor(p00[r], sh); p01[r] += __shfl_xor(p01[r], sh);
                    p10[r] += __shfl_xor(p10[r], sh); p11[r] += __shfl_xor(p11[r], sh);
                }
            }
            if (col == 0) {
                #pragma unroll
                for (int r = 0; r < 4; ++r) {
                    attn[re0 + r] = make_float2(p00[r] > 0.f ? p00[r] : 0.2f * p00[r],
                                                p01[r] > 0.f ? p01[r] : 0.2f * p01[r]);
                    attn[re1 + r] = make_float2(p10[r] > 0.f ? p10[r] : 0.2f * p10[r],
                                                p11[r] > 0.f ? p11[r] : 0.2f * p11[r]);
                }
            }
        }

        // ---------- PART 1: V ----------
        #pragma unroll
        for (int n = 0; n < 7; ++n) {
            int cl = n * 16 + col;
            float b = (cl < 100) ? wkv_b[100 + cl] : 0.f;
            acc0[n] = (f32x4){b, b, b, b};
            acc1[n] = (f32x4){b, b, b, b};
        }
        #pragma unroll
        for (int kc = 0; kc < 10; ++kc) {
            #pragma unroll
            for (int n = 0; n < 7; ++n) {
                short8b w = *(const short8b*)(&Wlds[(size_t)(W_HALF + ((kc * 7 + n) * 64 + lane) * 8)]);
                acc0[n] = __builtin_amdgcn_mfma_f32_16x16x32_bf16(af0[kc], w, acc0[n], 0, 0, 0);
                acc1[n] = __builtin_amdgcn_mfma_f32_16x16x32_bf16(af1[kc], w, acc1[n], 0, 0, 0);
            }
        }
        #pragma unroll
        for (int n = 0; n < 7; ++n) {
            int cl = n * 16 + col;
            if (cl < 100) {
                #pragma unroll
                for (int r = 0; r < 4; ++r) {
                    Vb[(size_t)(re0 + r) * 100 + cl] = f2bf(acc0[n][r]);
                    Vb[(size_t)(re1 + r) * 100 + cl] = f2bf(acc1[n][r]);
                }
            }
        }
    }
}

// ---------- segment softmax + weighted V reduce: one wave/node, 4-way unrolled chain ----------
__global__ __launch_bounds__(256) void k_soft(const float2* __restrict__ attn,
                                              const unsigned short* __restrict__ V,
                                              const int* __restrict__ off,
                                              float* __restrict__ agg) {
    const int lane = threadIdx.x & 63;
    const int n = blockIdx.x * 4 + (threadIdx.x >> 6);
    const int r0 = off[n], cnt = off[n + 1] - r0;
    float* __restrict__ aout = agg + (size_t)n * 100;
    if (cnt <= 0) {
        aout[lane] = 0.f;
        if (lane < 36) aout[64 + lane] = 0.f;
        return;
    }
    float m0 = -1e30f, m1 = -1e30f;
    for (int i = lane; i < cnt; i += 64) {
        float2 a = attn[r0 + i];
        m0 = fmaxf(m0, a.x); m1 = fmaxf(m1, a.y);
    }
    #pragma unroll
    for (int s = 1; s < 64; s <<= 1) {
        m0 = fmaxf(m0, __shfl_xor(m0, s));
        m1 = fmaxf(m1, __shfl_xor(m1, s));
    }
    float s0 = 0.f, s1 = 0.f;
    for (int i = lane; i < cnt; i += 64) {
        float2 a = attn[r0 + i];
        s0 += __expf(a.x - m0); s1 += __expf(a.y - m1);
    }
    #pragma unroll
    for (int s = 1; s < 64; s <<= 1) { s0 += __shfl_xor(s0, s); s1 += __shfl_xor(s1, s); }
    const float inv0 = 1.f / s0, inv1 = 1.f / s1;

    float aa0 = 0.f, aa1 = 0.f, aa2 = 0.f, aa3 = 0.f;
    float ab0 = 0.f, ab1 = 0.f, ab2 = 0.f, ab3 = 0.f;
    for (int base = 0; base < cnt; base += 64) {
        int i = base + lane;
        float e0 = 0.f, e1 = 0.f;
        if (i < cnt) {
            float2 a = attn[r0 + i];
            e0 = __expf(a.x - m0) * inv0;
            e1 = __expf(a.y - m1) * inv1;
        }
        int lim = min(64, cnt - base);
        const unsigned short* __restrict__ vrow = V + (size_t)(r0 + base) * 100;
        int j = 0;
        for (; j + 4 <= lim; j += 4) {
            float q00 = __shfl(e0, j),     q10 = __shfl(e1, j);
            float q01 = __shfl(e0, j + 1), q11 = __shfl(e1, j + 1);
            float q02 = __shfl(e0, j + 2), q12 = __shfl(e1, j + 2);
            float q03 = __shfl(e0, j + 3), q13 = __shfl(e1, j + 3);
            const unsigned short* w0 = vrow + (size_t)j * 100;
            float pa0 = (lane < 50) ? q00 : q10;
            float pa1 = (lane < 50) ? q01 : q11;
            float pa2 = (lane < 50) ? q02 : q12;
            float pa3 = (lane < 50) ? q03 : q13;
            aa0 = fmaf(pa0, bf2f(w0[lane]),       aa0);
            aa1 = fmaf(pa1, bf2f(w0[100 + lane]), aa1);
            aa2 = fmaf(pa2, bf2f(w0[200 + lane]), aa2);
            aa3 = fmaf(pa3, bf2f(w0[300 + lane]), aa3);
            if (lane < 36) {
                ab0 = fmaf(q10, bf2f(w0[64 + lane]),  ab0);
                ab1 = fmaf(q11, bf2f(w0[164 + lane]), ab1);
                ab2 = fmaf(q12, bf2f(w0[264 + lane]), ab2);
                ab3 = fmaf(q13, bf2f(w0[364 + lane]), ab3);
            }
        }
        for (; j < lim; ++j) {
            float q0 = __shfl(e0, j), q1 = __shfl(e1, j);
            const unsigned short* w0 = vrow + (size_t)j * 100;
            float pa = (lane < 50) ? q0 : q1;
            aa0 = fmaf(pa, bf2f(w0[lane]), aa0);
            if (lane < 36) ab0 = fmaf(q1, bf2f(w0[64 + lane]), ab0);
        }
    }
    aout[lane] = (aa0 + aa1) + (aa2 + aa3);
    if (lane < 36) aout[64 + lane] = (ab0 + ab1) + (ab2 + ab3);
}

// ---------- out proj + relu + layernorm: 8 nodes/block, coalesced wout_t ----------
__global__ __launch_bounds__(128) void k_out(const float* __restrict__ agg,
                                             const float* __restrict__ dst_h,
                                             const float* __restrict__ wout_t,
                                             const float* __restrict__ wout_b,
                                             const float* __restrict__ ln_g,
                                             const float* __restrict__ ln_b,
                                             float* __restrict__ out) {
    __shared__ float Fs[8][200];
    __shared__ float red[8][128];
    const int n0 = blockIdx.x * 8, t = threadIdx.x;
    for (int idx = t; idx < 1600; idx += 128) {
        int n = idx / 200, i = idx % 200;
        Fs[n][i] = (i < 100) ? agg[(size_t)(n0 + n) * 100 + i]
                             : dst_h[(size_t)(n0 + n) * 100 + (i - 100)];
    }
    __syncthreads();
    float v[8] = {0.f, 0.f, 0.f, 0.f, 0.f, 0.f, 0.f, 0.f};
    if (t < 100) {
        float b = wout_b[t];
        #pragma unroll
        for (int n = 0; n < 8; ++n) v[n] = b;
        for (int i = 0; i < 200; ++i) {
            float w = wout_t[i * 100 + t];
            #pragma unroll
            for (int n = 0; n < 8; ++n) v[n] = fmaf(Fs[n][i], w, v[n]);
        }
        #pragma unroll
        for (int n = 0; n < 8; ++n) v[n] = fmaxf(v[n], 0.f);
    }
    #pragma unroll
    for (int n = 0; n < 8; ++n) red[n][t] = (t < 100) ? v[n] : 0.f;
    __syncthreads();
    for (int s = 64; s > 0; s >>= 1) {
        if (t < s) {
            #pragma unroll
            for (int n = 0; n < 8; ++n) red[n][t] += red[n][t + s];
        }
        __syncthreads();
    }
    float mu[8];
    #pragma unroll
    for (int n = 0; n < 8; ++n) mu[n] = red[n][0] * 0.01f;
    __syncthreads();
    #pragma unroll
    for (int n = 0; n < 8; ++n) {
        float dv = (t < 100) ? (v[n] - mu[n]) : 0.f;
        red[n][t] = dv * dv;
    }
    __syncthreads();
    for (int s = 64; s > 0; s >>= 1) {
        if (t < s) {
            #pragma unroll
            for (int n = 0; n < 8; ++n) red[n][t] += red[n][t + s];
        }
        __syncthreads();
    }
    if (t < 100) {
        #pragma unroll
        for (int n = 0; n < 8; ++n) {
            float var = red[n][0] * 0.01f;
            out[(size_t)(n0 + n) * 100 + t] =
                (v[n] - mu[n]) * rsqrtf(var + LN_EPS) * ln_g[t] + ln_b[t];
        }
    }
}

extern "C" void kernel_launch(void* const* d_in, const int* in_sizes, int n_in,
                              void* d_out, int out_size, void* d_ws, size_t ws_size,
                              hipStream_t stream) {
    const float* dst_h   = (const float*)d_in[0];
    const float* src_h   = (const float*)d_in[1];
    const float* efeat   = (const float*)d_in[2];
    const float* td      = (const float*)d_in[3];
    const int*   edst    = (const int*)  d_in[4];
    const float* time_w  = (const float*)d_in[5];
    const float* time_b  = (const float*)d_in[6];
    const float* wq_w    = (const float*)d_in[7];
    const float* wq_b    = (const float*)d_in[8];
    const float* wkv_w   = (const float*)d_in[9];
    const float* wkv_b   = (const float*)d_in[10];
    const float* wout_w  = (const float*)d_in[11];
    const float* wout_b  = (const float*)d_in[12];
    const float* ln_g    = (const float*)d_in[13];
    const float* ln_b    = (const float*)d_in[14];
    float* out = (float*)d_out;

    char* ws = (char*)d_ws;
    size_t off = 0;
    auto carve = [&](size_t bytes) { char* p = ws + off; off = (off + bytes + 255) & ~(size_t)255; return p; };
    float*          Q     = (float*)carve((size_t)N_DST * 100 * 4);
    float2*         attn  = (float2*)carve((size_t)N_EDGE * 2 * 4);
    unsigned short* Vb    = (unsigned short*)carve((size_t)N_EDGE * 100 * 2);
    float*          agg   = (float*)carve((size_t)N_DST * 100 * 4);
    unsigned short* Wvp   = (unsigned short*)carve(W_TOT * 2);
    float*          zq    = (float*)carve(100 * 4);
    float*          woutT = (float*)carve(20000 * 4);
    int*            offs  = (int*)carve((size_t)(N_DST + 1) * 4);

    // raise dynamic-LDS cap for k_edge (idempotent; not a stream op)
    (void)hipFuncSetAttribute((const void*)k_edge,
                              hipFuncAttributeMaxDynamicSharedMemorySize, W_TOT * 2);

    k_prep<<<(W_TOT + 100 + 20000 + 255) / 256, 256, 0, stream>>>(
        wkv_w, wq_w, wq_b, time_b, wout_w, Wvp, zq, woutT);
    k_offsets<<<(N_DST + 1 + 255) / 256, 256, 0, stream>>>(edst, offs);
    k_q<<<N_DST / 16, 128, 0, stream>>>(dst_h, wq_w, zq, Q);
    k_edge<<<512, 256, W_TOT * 2, stream>>>(src_h, efeat, td, edst, time_w, time_b,
                                            Wvp, wkv_b, Q, Vb, attn);
    k_soft<<<N_DST / 4, 256, 0, stream>>>(attn, Vb, offs, agg);
    k_out<<<N_DST / 8, 128, 0, stream>>>(agg, dst_h, woutT, wout_b, ln_g, ln_b, out);
}